// Round 1
// baseline (561.434 us; speedup 1.0000x reference)
//
#include <hip/hip_runtime.h>

// out[b,o] = sum_g as[b,g]*ws[o,g]*dot(x4[b,g*128..],w4[o,..]) + bias[o]
// B=4096, O=11008, K=4096, GS=128, G=32. Inputs normalized by harness to f32.
// R5: phase-split main loop with COUNTED vmcnt (never drains), raw s_barrier,
//     setprio around MFMA clusters, scale loads pipelined one group ahead,
//     XCD-bijective block swizzle (8 xcd x 4 bm-stripes x 86 bn), coalesced
//     LDS-tiled scale transpose. Deterministic VMEM queue per group:
//     issue stageA(4), stageB(4), scales(8); waits vmcnt(12)/16/12.

#define B_DIM 4096
#define O_DIM 11008
#define K_DIM 4096
#define G_NUM 32

#define NX32 8388608u    // int32 elements of xq
#define NW32 22544384u   // int32 elements of wq
#define X8_BYTES  16777216u
#define W8_BYTES  45088768u

typedef int   i32x4 __attribute__((ext_vector_type(4)));
typedef float f32x4 __attribute__((ext_vector_type(4)));

// ---------------- prepass 1: unpack nibbles -> signed int8 ----------------
__device__ __forceinline__ unsigned pack2(int v) {
    int t = v ^ 0x88;                                  // (q^8)-8 per nibble
    unsigned lo = (unsigned)(((t & 15) - 8) & 0xFF);
    unsigned hi = (unsigned)((((t >> 4) & 15) - 8) & 0xFF);
    return lo | (hi << 8);
}

__global__ __launch_bounds__(256)
void unpack_kernel(const int* __restrict__ xq, const int* __restrict__ wq,
                   unsigned char* __restrict__ X8, unsigned char* __restrict__ W8) {
    unsigned t = blockIdx.x * 256u + threadIdx.x;      // one thread: 8 int32 -> 16 B
    const int* src;
    unsigned char* dst;
    if (t < NX32 / 8) {
        src = xq + (size_t)t * 8;
        dst = X8 + (size_t)t * 16;
    } else {
        unsigned j = t - NX32 / 8;
        src = wq + (size_t)j * 8;
        dst = W8 + (size_t)j * 16;
    }
    int4 v0 = ((const int4*)src)[0];
    int4 v1 = ((const int4*)src)[1];
    uint4 o;
    o.x = pack2(v0.x) | (pack2(v0.y) << 16);
    o.y = pack2(v0.z) | (pack2(v0.w) << 16);
    o.z = pack2(v1.x) | (pack2(v1.y) << 16);
    o.w = pack2(v1.z) | (pack2(v1.w) << 16);
    *(uint4*)dst = o;
}

// ------------- prepass 2: coalesced LDS-tiled scale transpose -------------
// as_: [4096][32] -> asT [32][4096];  ws_: [11008][32] -> wsT [32][11008].
// Block transposes a 64-row x 32-col panel. Grid = 64 (as) + 172 (ws).
__global__ __launch_bounds__(256)
void tscale_kernel(const float* __restrict__ as_, const float* __restrict__ ws_,
                   float* __restrict__ asT, float* __restrict__ wsT) {
    __shared__ float tile[64][33];
    const int blk = blockIdx.x, t = threadIdx.x;
    const float* src; float* dst; int R0, RTOT;
    if (blk < 64) { src = as_; dst = asT; R0 = blk * 64;        RTOT = B_DIM; }
    else          { src = ws_; dst = wsT; R0 = (blk - 64) * 64; RTOT = O_DIM; }

    // read: thread t -> row t>>2, cols (t&3)*8..+7 (fully coalesced 128B rows)
    {
        const int r = t >> 2, cc = (t & 3) * 8;
        const float* p = src + (size_t)(R0 + r) * G_NUM + cc;
        f32x4 v0 = *(const f32x4*)p;
        f32x4 v1 = *(const f32x4*)(p + 4);
#pragma unroll
        for (int k = 0; k < 4; ++k) { tile[r][cc + k] = v0[k]; tile[r][cc + 4 + k] = v1[k]; }
    }
    __syncthreads();
    // write: thread t -> g = t>>3, b-chunk (t&7)*8 (256B contiguous per g-row)
    {
        const int g = t >> 3, bc = (t & 7) * 8;
        f32x4 w0, w1;
#pragma unroll
        for (int k = 0; k < 4; ++k) { w0[k] = tile[bc + k][g]; w1[k] = tile[bc + 4 + k][g]; }
        float* q = dst + (size_t)g * RTOT + R0 + bc;
        *(f32x4*)q = w0;
        *(f32x4*)(q + 4) = w1;
    }
}

// ---------------- GEMM ----------------
__global__ __launch_bounds__(256, 2)
void gemm_i8(const unsigned char* __restrict__ X8, const unsigned char* __restrict__ W8,
             const float* __restrict__ asT, const float* __restrict__ wsT,
             const float* __restrict__ bias, float* __restrict__ out) {
    __shared__ __align__(16) unsigned char A0[16384];
    __shared__ __align__(16) unsigned char B0[16384];
    __shared__ __align__(16) unsigned char A1[16384];
    __shared__ __align__(16) unsigned char B1[16384];

    const int tid  = threadIdx.x;
    const int wv   = tid >> 6;
    const int lane = tid & 63;
    const int quad = lane >> 4;
    const int lq   = lane & 15;

    // XCD-bijective swizzle: 2752 blocks = 8 xcds * (4 bm-stripes * 86 bn).
    // Each XCD keeps a 4-row X8 stripe (2MB) L2-resident while sweeping bn.
    const unsigned lin = blockIdx.x;
    const unsigned xcd = lin & 7u, pos = lin >> 3;
    const int bn = (int)(pos % 86u);
    const int bm = (int)((xcd << 2) + pos / 86u);

    const int wm   = (wv & 1) << 6;
    const int wn   = (wv >> 1) << 6;

    f32x4 facc[4][4] = {};

    const int l8 = lane >> 3;
    const int c8 = lane & 7;
    const int sw_chunk = ((c8 ^ l8) << 4);            // XOR store-side swizzle
    const size_t xrow0 = (size_t)(bm * 128) * K_DIM;
    const size_t wrow0 = (size_t)(bn * 128) * K_DIM;
    const int abase = bm * 128 + wm + (quad << 2);
    const int wbase = bn * 128 + wn + lq;
    const int pa0 = ((quad ^ (lq & 7)) << 4);
    const int pa1 = (((4 + quad) ^ (lq & 7)) << 4);

    auto stageA = [&](int g, unsigned char* Ad) {     // 4 global_load_lds
        const int gb = g << 7;
#pragma unroll
        for (int s = 0; s < 4; ++s) {
            const int slab = (wv << 2) + s;
            const int row  = (slab << 3) + l8;
            const unsigned char* gp = X8 + xrow0 + (size_t)row * K_DIM + gb + sw_chunk;
            __builtin_amdgcn_global_load_lds(
                (const __attribute__((address_space(1))) void*)gp,
                (__attribute__((address_space(3))) void*)(Ad + (slab << 10)), 16, 0, 0);
        }
    };
    auto stageB = [&](int g, unsigned char* Bd) {     // 4 global_load_lds
        const int gb = g << 7;
#pragma unroll
        for (int s = 0; s < 4; ++s) {
            const int slab = (wv << 2) + s;
            const int row  = (slab << 3) + l8;
            const unsigned char* gp = W8 + wrow0 + (size_t)row * K_DIM + gb + sw_chunk;
            __builtin_amdgcn_global_load_lds(
                (const __attribute__((address_space(1))) void*)gp,
                (__attribute__((address_space(3))) void*)(Bd + (slab << 10)), 16, 0, 0);
        }
    };
    auto loadScales = [&](int g, f32x4 (&asr)[4], float (&wsn)[4]) {  // 8 vm ops
#pragma unroll
        for (int i = 0; i < 4; ++i)
            asr[i] = *(const f32x4*)&asT[(g << 12) + abase + (i << 4)];
#pragma unroll
        for (int j = 0; j < 4; ++j)
            wsn[j] = wsT[(size_t)g * O_DIM + wbase + (j << 4)];
    };

    f32x4 asrA[4], asrB[4];
    float wsnA[4], wsnB[4];

    // Per group g, vm issue order: stageA(g+1)[4], stageB(g+1)[4], scales(g+1)[8].
    // Queue entering group g: [Bstage(g) 4, scales(g) 8] = 12.
    auto body = [&](int g, const unsigned char* Ac, const unsigned char* Bc,
                    unsigned char* An, unsigned char* Bn,
                    f32x4 (&asrC)[4], float (&wsnC)[4],
                    f32x4 (&asrN)[4], float (&wsnN)[4]) {
        const int gn = (g + 1 < G_NUM) ? g + 1 : G_NUM - 1;   // clamp: uniform tail
        i32x4 gacc[4][4] = {};
        i32x4 av0[4], bv0[4], av1[4], bv1[4];

        // ---- P1: A-frags ks0; issue next A-tile ----
#pragma unroll
        for (int i = 0; i < 4; ++i)
            av0[i] = *(const i32x4*)&Ac[((wm + (i << 4) + lq) << 7) + pa0];
        stageA(gn, An);
        asm volatile("s_waitcnt vmcnt(12)" ::: "memory");     // Bstage(g) done
        __builtin_amdgcn_s_barrier();                          // B-tile(g) visible
        __builtin_amdgcn_sched_barrier(0);

        // ---- P2: B-frags ks0; issue next B-tile; MFMA ks0 ----
#pragma unroll
        for (int j = 0; j < 4; ++j)
            bv0[j] = *(const i32x4*)&Bc[((wn + (j << 4) + lq) << 7) + pa0];
        stageB(gn, Bn);
        asm volatile("s_waitcnt lgkmcnt(0)" ::: "memory");
        __builtin_amdgcn_sched_barrier(0);
        __builtin_amdgcn_s_setprio(1);
#pragma unroll
        for (int i = 0; i < 4; ++i)
#pragma unroll
            for (int j = 0; j < 4; ++j)
                gacc[i][j] = __builtin_amdgcn_mfma_i32_16x16x64_i8(av0[i], bv0[j], gacc[i][j], 0, 0, 0);
        __builtin_amdgcn_s_setprio(0);

        // ---- P3: frags ks1; issue next scales; MFMA ks1; rescale ----
#pragma unroll
        for (int i = 0; i < 4; ++i)
            av1[i] = *(const i32x4*)&Ac[((wm + (i << 4) + lq) << 7) + pa1];
#pragma unroll
        for (int j = 0; j < 4; ++j)
            bv1[j] = *(const i32x4*)&Bc[((wn + (j << 4) + lq) << 7) + pa1];
        loadScales(gn, asrN, wsnN);
        asm volatile("s_waitcnt lgkmcnt(0)" ::: "memory");
        __builtin_amdgcn_sched_barrier(0);
        __builtin_amdgcn_s_setprio(1);
#pragma unroll
        for (int i = 0; i < 4; ++i)
#pragma unroll
            for (int j = 0; j < 4; ++j)
                gacc[i][j] = __builtin_amdgcn_mfma_i32_16x16x64_i8(av1[i], bv1[j], gacc[i][j], 0, 0, 0);
        __builtin_amdgcn_s_setprio(0);

        asm volatile("s_waitcnt vmcnt(16)" ::: "memory");     // scales(g) arrived
        __builtin_amdgcn_sched_barrier(0);
#pragma unroll
        for (int i = 0; i < 4; ++i)
#pragma unroll
            for (int j = 0; j < 4; ++j) {
                f32x4 s = asrC[i] * wsnC[j];
                f32x4 gf;
#pragma unroll
                for (int r = 0; r < 4; ++r) gf[r] = (float)gacc[i][j][r];
                facc[i][j] += gf * s;
            }
        asm volatile("s_waitcnt vmcnt(12)" ::: "memory");     // Astage(g+1) done
        __builtin_amdgcn_s_barrier();                          // A-tile(g+1) visible
        __builtin_amdgcn_sched_barrier(0);
    };

    // prologue: establish [Bstage(0) 4, scales(0) 8] = 12 in flight, A-tile(0) visible
    stageA(0, A0);
    stageB(0, B0);
    loadScales(0, asrA, wsnA);
    asm volatile("s_waitcnt vmcnt(12)" ::: "memory");
    __builtin_amdgcn_s_barrier();
    __builtin_amdgcn_sched_barrier(0);

#pragma unroll 1
    for (int g2 = 0; g2 < G_NUM; g2 += 2) {
        body(g2,     A0, B0, A1, B1, asrA, wsnA, asrB, wsnB);
        body(g2 + 1, A1, B1, A0, B0, asrB, wsnB, asrA, wsnA);
    }

    // epilogue (f32 output); C/D: col=lq, row=quad*4+r
    const int n0 = bn * 128 + wn + lq;
    const int m0 = bm * 128 + wm + (quad << 2);
    float bvs[4];
#pragma unroll
    for (int j = 0; j < 4; ++j) bvs[j] = bias[n0 + (j << 4)];
#pragma unroll
    for (int i = 0; i < 4; ++i) {
#pragma unroll
        for (int r = 0; r < 4; ++r) {
            float* orow = out + (size_t)(m0 + (i << 4) + r) * O_DIM;
#pragma unroll
            for (int j = 0; j < 4; ++j)
                orow[n0 + (j << 4)] = facc[i][j][r] + bvs[j];
        }
    }
}

extern "C" void kernel_launch(void* const* d_in, const int* in_sizes, int n_in,
                              void* d_out, int out_size, void* d_ws, size_t ws_size,
                              hipStream_t stream) {
    const int*   xq   = (const int*)d_in[0];
    const float* as_  = (const float*)d_in[1];
    const int*   wq   = (const int*)d_in[2];
    const float* ws_  = (const float*)d_in[3];
    const float* bias = (const float*)d_in[4];
    float* out        = (float*)d_out;

    unsigned char* X8 = (unsigned char*)d_ws;
    unsigned char* W8 = X8 + X8_BYTES;
    float* asT = (float*)((unsigned char*)d_ws + X8_BYTES + W8_BYTES);
    float* wsT = asT + (size_t)G_NUM * B_DIM;

    unpack_kernel<<<(NX32 + NW32) / 8 / 256, 256, 0, stream>>>(xq, wq, X8, W8);
    tscale_kernel<<<64 + 172, 256, 0, stream>>>(as_, ws_, asT, wsT);
    gemm_i8<<<dim3((B_DIM / 128) * (O_DIM / 128)), 256, 0, stream>>>(X8, W8, asT, wsT, bias, out);
}

// Round 2
// 544.864 us; speedup vs baseline: 1.0304x; 1.0304x over previous
//
#include <hip/hip_runtime.h>

// out[b,o] = sum_g as[b,g]*ws[o,g]*dot(x4[b,g*128..],w4[o,..]) + bias[o]
// B=4096, O=11008, K=4096, GS=128, G=32. Inputs normalized by harness to f32.
// R6: grid mapping reverted to dim3(32,86) (R1's xcd swizzle killed W-tile L2
//     sharing: FETCH 270->765MB). Main loop: ONE raw s_barrier per group with
//     counted vmcnt that never drains: per group issue [stage(g+1) x8,
//     scales(g+1) x8]; waits vmcnt(8) at top (stage(g) done, scales(g) fly),
//     vmcnt(8) pre-rescale (scales(g) done, stage(g+1) flies ACROSS barrier).
//     setprio(1) around MFMA clusters; sched_barrier(0) after each waitcnt.

#define B_DIM 4096
#define O_DIM 11008
#define K_DIM 4096
#define G_NUM 32

#define NX32 8388608u    // int32 elements of xq
#define NW32 22544384u   // int32 elements of wq
#define X8_BYTES  16777216u
#define W8_BYTES  45088768u

typedef int   i32x4 __attribute__((ext_vector_type(4)));
typedef float f32x4 __attribute__((ext_vector_type(4)));

// ---------------- prepass 1: unpack nibbles -> signed int8 ----------------
__device__ __forceinline__ unsigned pack2(int v) {
    int t = v ^ 0x88;                                  // (q^8)-8 per nibble
    unsigned lo = (unsigned)(((t & 15) - 8) & 0xFF);
    unsigned hi = (unsigned)((((t >> 4) & 15) - 8) & 0xFF);
    return lo | (hi << 8);
}

__global__ __launch_bounds__(256)
void unpack_kernel(const int* __restrict__ xq, const int* __restrict__ wq,
                   unsigned char* __restrict__ X8, unsigned char* __restrict__ W8) {
    unsigned t = blockIdx.x * 256u + threadIdx.x;      // one thread: 8 int32 -> 16 B
    const int* src;
    unsigned char* dst;
    if (t < NX32 / 8) {
        src = xq + (size_t)t * 8;
        dst = X8 + (size_t)t * 16;
    } else {
        unsigned j = t - NX32 / 8;
        src = wq + (size_t)j * 8;
        dst = W8 + (size_t)j * 16;
    }
    int4 v0 = ((const int4*)src)[0];
    int4 v1 = ((const int4*)src)[1];
    uint4 o;
    o.x = pack2(v0.x) | (pack2(v0.y) << 16);
    o.y = pack2(v0.z) | (pack2(v0.w) << 16);
    o.z = pack2(v1.x) | (pack2(v1.y) << 16);
    o.w = pack2(v1.z) | (pack2(v1.w) << 16);
    *(uint4*)dst = o;
}

// ------------- prepass 2: coalesced LDS-tiled scale transpose -------------
__global__ __launch_bounds__(256)
void tscale_kernel(const float* __restrict__ as_, const float* __restrict__ ws_,
                   float* __restrict__ asT, float* __restrict__ wsT) {
    __shared__ float tile[64][33];
    const int blk = blockIdx.x, t = threadIdx.x;
    const float* src; float* dst; int R0, RTOT;
    if (blk < 64) { src = as_; dst = asT; R0 = blk * 64;        RTOT = B_DIM; }
    else          { src = ws_; dst = wsT; R0 = (blk - 64) * 64; RTOT = O_DIM; }
    {
        const int r = t >> 2, cc = (t & 3) * 8;
        const float* p = src + (size_t)(R0 + r) * G_NUM + cc;
        f32x4 v0 = *(const f32x4*)p;
        f32x4 v1 = *(const f32x4*)(p + 4);
#pragma unroll
        for (int k = 0; k < 4; ++k) { tile[r][cc + k] = v0[k]; tile[r][cc + 4 + k] = v1[k]; }
    }
    __syncthreads();
    {
        const int g = t >> 3, bc = (t & 7) * 8;
        f32x4 w0, w1;
#pragma unroll
        for (int k = 0; k < 4; ++k) { w0[k] = tile[bc + k][g]; w1[k] = tile[bc + 4 + k][g]; }
        float* q = dst + (size_t)g * RTOT + R0 + bc;
        *(f32x4*)q = w0;
        *(f32x4*)(q + 4) = w1;
    }
}

// ---------------- GEMM ----------------
__global__ __launch_bounds__(256, 2)
void gemm_i8(const unsigned char* __restrict__ X8, const unsigned char* __restrict__ W8,
             const float* __restrict__ asT, const float* __restrict__ wsT,
             const float* __restrict__ bias, float* __restrict__ out) {
    __shared__ __align__(16) unsigned char A0[16384];
    __shared__ __align__(16) unsigned char B0[16384];
    __shared__ __align__(16) unsigned char A1[16384];
    __shared__ __align__(16) unsigned char B1[16384];

    const int tid  = threadIdx.x;
    const int wv   = tid >> 6;
    const int lane = tid & 63;
    const int quad = lane >> 4;
    const int lq   = lane & 15;
    const int bm   = blockIdx.x;          // reverted mapping: 4 bm share bn per XCD
    const int bn   = blockIdx.y;
    const int wm   = (wv & 1) << 6;
    const int wn   = (wv >> 1) << 6;

    f32x4 facc[4][4] = {};

    const int l8 = lane >> 3;
    const int c8 = lane & 7;
    const int sw_chunk = ((c8 ^ l8) << 4);            // XOR store-side swizzle
    const size_t xrow0 = (size_t)(bm * 128) * K_DIM;
    const size_t wrow0 = (size_t)(bn * 128) * K_DIM;
    const int abase = bm * 128 + wm + (quad << 2);
    const int wbase = bn * 128 + wn + lq;
    const int pa0 = ((quad ^ (lq & 7)) << 4);
    const int pa1 = (((4 + quad) ^ (lq & 7)) << 4);

    auto stageAB = [&](int g, unsigned char* Ad, unsigned char* Bd) {  // 8 vm ops
        const int gb = g << 7;
#pragma unroll
        for (int s = 0; s < 4; ++s) {
            const int slab = (wv << 2) + s;
            const int row  = (slab << 3) + l8;
            const unsigned char* gpA = X8 + xrow0 + (size_t)row * K_DIM + gb + sw_chunk;
            __builtin_amdgcn_global_load_lds(
                (const __attribute__((address_space(1))) void*)gpA,
                (__attribute__((address_space(3))) void*)(Ad + (slab << 10)), 16, 0, 0);
        }
#pragma unroll
        for (int s = 0; s < 4; ++s) {
            const int slab = (wv << 2) + s;
            const int row  = (slab << 3) + l8;
            const unsigned char* gpB = W8 + wrow0 + (size_t)row * K_DIM + gb + sw_chunk;
            __builtin_amdgcn_global_load_lds(
                (const __attribute__((address_space(1))) void*)gpB,
                (__attribute__((address_space(3))) void*)(Bd + (slab << 10)), 16, 0, 0);
        }
    };
    auto loadScales = [&](int g, f32x4 (&asr)[4], float (&wsn)[4]) {   // 8 vm ops
#pragma unroll
        for (int i = 0; i < 4; ++i)
            asr[i] = *(const f32x4*)&asT[(g << 12) + abase + (i << 4)];
#pragma unroll
        for (int j = 0; j < 4; ++j)
            wsn[j] = wsT[(size_t)g * O_DIM + wbase + (j << 4)];
    };

    f32x4 asrA[4], asrB[4];
    float wsnA[4], wsnB[4];

    // Loop invariant at top of group g: outstanding vmem = [stage(g) 8, scales(g) 8].
    auto body = [&](int g, const unsigned char* Ac, const unsigned char* Bc,
                    unsigned char* An, unsigned char* Bn,
                    f32x4 (&asrC)[4], float (&wsnC)[4],
                    f32x4 (&asrN)[4], float (&wsnN)[4]) {
        const int gn = (g + 1 < G_NUM) ? g + 1 : G_NUM - 1;   // clamp: uniform tail
        i32x4 gacc[4][4] = {};
        i32x4 av0[4], bv0[4], av1[4], bv1[4];

        asm volatile("s_waitcnt vmcnt(8)" ::: "memory");   // stage(g) landed
        __builtin_amdgcn_s_barrier();                       // tiles(g) visible to all
        __builtin_amdgcn_sched_barrier(0);

        // ks0 fragment reads; next-tile stage flies from here to top of g+1
#pragma unroll
        for (int i = 0; i < 4; ++i)
            av0[i] = *(const i32x4*)&Ac[((wm + (i << 4) + lq) << 7) + pa0];
#pragma unroll
        for (int j = 0; j < 4; ++j)
            bv0[j] = *(const i32x4*)&Bc[((wn + (j << 4) + lq) << 7) + pa0];
        stageAB(gn, An, Bn);

        asm volatile("s_waitcnt lgkmcnt(0)" ::: "memory");
        __builtin_amdgcn_sched_barrier(0);
        __builtin_amdgcn_s_setprio(1);
#pragma unroll
        for (int i = 0; i < 4; ++i)
#pragma unroll
            for (int j = 0; j < 4; ++j)
                gacc[i][j] = __builtin_amdgcn_mfma_i32_16x16x64_i8(av0[i], bv0[j], gacc[i][j], 0, 0, 0);
        __builtin_amdgcn_s_setprio(0);

        // ks1
#pragma unroll
        for (int i = 0; i < 4; ++i)
            av1[i] = *(const i32x4*)&Ac[((wm + (i << 4) + lq) << 7) + pa1];
#pragma unroll
        for (int j = 0; j < 4; ++j)
            bv1[j] = *(const i32x4*)&Bc[((wn + (j << 4) + lq) << 7) + pa1];
        asm volatile("s_waitcnt lgkmcnt(0)" ::: "memory");
        __builtin_amdgcn_sched_barrier(0);
        __builtin_amdgcn_s_setprio(1);
#pragma unroll
        for (int i = 0; i < 4; ++i)
#pragma unroll
            for (int j = 0; j < 4; ++j)
                gacc[i][j] = __builtin_amdgcn_mfma_i32_16x16x64_i8(av1[i], bv1[j], gacc[i][j], 0, 0, 0);
        __builtin_amdgcn_s_setprio(0);

        asm volatile("s_waitcnt vmcnt(8)" ::: "memory");   // scales(g) arrived; stage(g+1) STAYS in flight
        __builtin_amdgcn_sched_barrier(0);
#pragma unroll
        for (int i = 0; i < 4; ++i)
#pragma unroll
            for (int j = 0; j < 4; ++j) {
                f32x4 s = asrC[i] * wsnC[j];
                f32x4 gf;
#pragma unroll
                for (int r = 0; r < 4; ++r) gf[r] = (float)gacc[i][j][r];
                facc[i][j] += gf * s;
            }
        loadScales(gn, asrN, wsnN);                         // restores invariant
    };

    // prologue: establish [stage(0) 8, scales(0) 8]
    stageAB(0, A0, B0);
    loadScales(0, asrA, wsnA);

#pragma unroll 1
    for (int g2 = 0; g2 < G_NUM; g2 += 2) {
        body(g2,     A0, B0, A1, B1, asrA, wsnA, asrB, wsnB);
        body(g2 + 1, A1, B1, A0, B0, asrB, wsnB, asrA, wsnA);
    }

    // epilogue (f32 output); C/D: col=lq, row=quad*4+r
    const int n0 = bn * 128 + wn + lq;
    const int m0 = bm * 128 + wm + (quad << 2);
    float bvs[4];
#pragma unroll
    for (int j = 0; j < 4; ++j) bvs[j] = bias[n0 + (j << 4)];
#pragma unroll
    for (int i = 0; i < 4; ++i) {
#pragma unroll
        for (int r = 0; r < 4; ++r) {
            float* orow = out + (size_t)(m0 + (i << 4) + r) * O_DIM;
#pragma unroll
            for (int j = 0; j < 4; ++j)
                orow[n0 + (j << 4)] = facc[i][j][r] + bvs[j];
        }
    }
}

extern "C" void kernel_launch(void* const* d_in, const int* in_sizes, int n_in,
                              void* d_out, int out_size, void* d_ws, size_t ws_size,
                              hipStream_t stream) {
    const int*   xq   = (const int*)d_in[0];
    const float* as_  = (const float*)d_in[1];
    const int*   wq   = (const int*)d_in[2];
    const float* ws_  = (const float*)d_in[3];
    const float* bias = (const float*)d_in[4];
    float* out        = (float*)d_out;

    unsigned char* X8 = (unsigned char*)d_ws;
    unsigned char* W8 = X8 + X8_BYTES;
    float* asT = (float*)((unsigned char*)d_ws + X8_BYTES + W8_BYTES);
    float* wsT = asT + (size_t)G_NUM * B_DIM;

    unpack_kernel<<<(NX32 + NW32) / 8 / 256, 256, 0, stream>>>(xq, wq, X8, W8);
    tscale_kernel<<<64 + 172, 256, 0, stream>>>(as_, ws_, asT, wsT);
    gemm_i8<<<dim3(B_DIM / 128, O_DIM / 128), 256, 0, stream>>>(X8, W8, asT, wsT, bias, out);
}